// Round 5
// baseline (200.724 us; speedup 1.0000x reference)
//
#include <hip/hip_runtime.h>

// out[e, k, i, j] = rf[e][i] * na[sender[e]][k] * ea[e][j]
// rf[e][i] = b[i] + sum_m radial[e][m] * W[i][m]
// out offset = e*512 + k*128 + i*16 + j ; duplicated at +E*512.
//
// Stream-split variant: work item u in [0, E*64). stream = u>>23 (E*32 = 2^23),
// so half the grid writes only combined_r, half only combined_i — each wave
// issues ONE monotonically ascending nt-store stream (fill-kernel-like),
// instead of alternating between regions 512 MB apart. Compute is duplicated
// (negligible); input reads double to ~52 MB (+2.4% traffic).

typedef float f32x4 __attribute__((ext_vector_type(4)));

__global__ void edge_embed_kernel(const int* __restrict__ edge_index,
                                  const float* __restrict__ radial,
                                  const float* __restrict__ ea,
                                  const float* __restrict__ na,
                                  const float* __restrict__ W,
                                  const float* __restrict__ b,
                                  float* __restrict__ out,
                                  long long total,      // E * 64
                                  long long half_items, // E * 32
                                  long long half_off)   // E * 512
{
    long long u = (long long)blockIdx.x * blockDim.x + threadIdx.x;
    const long long stride = (long long)gridDim.x * blockDim.x;

    for (; u < total; u += stride) {
        const long long v = (u < half_items) ? u : (u - half_items);
        float* __restrict__ dst = (u < half_items) ? out : (out + half_off);

        const int t = (int)(v & 31);
        const long long e = v >> 5;
        const int i  = t >> 2;
        const int j4 = t & 3;

        // rf[i] = b[i] + radial[e,:] . W[i,:]  (wave-broadcast L1 hits)
        const float* __restrict__ r = radial + e * 8;
        const float* __restrict__ w = W + i * 8;
        float rf = b[i];
        #pragma unroll
        for (int m = 0; m < 8; ++m) rf = fmaf(r[m], w[m], rf);

        const int s = edge_index[e];
        const f32x4 na4 = *reinterpret_cast<const f32x4*>(na + (long long)s * 4);
        const f32x4 ea4 = *reinterpret_cast<const f32x4*>(ea + e * 16 + j4 * 4);

        const long long base = e * 512 + (long long)t * 4;  // floats

        #pragma unroll
        for (int k = 0; k < 4; ++k) {
            const float c = rf * na4[k];
            f32x4 o = c * ea4;
            __builtin_nontemporal_store(o, reinterpret_cast<f32x4*>(dst + base + k * 128));
        }
    }
}

extern "C" void kernel_launch(void* const* d_in, const int* in_sizes, int n_in,
                              void* d_out, int out_size, void* d_ws, size_t ws_size,
                              hipStream_t stream) {
    const int*   edge_index = (const int*)d_in[0];   // (2, E)
    const float* radial     = (const float*)d_in[1]; // (E, 8)
    const float* ea         = (const float*)d_in[2]; // (E, 16)
    const float* na         = (const float*)d_in[3]; // (N, 4)
    const float* W          = (const float*)d_in[4]; // (8, 8)
    const float* b          = (const float*)d_in[5]; // (8,)
    float* out = (float*)d_out;

    const long long E = in_sizes[0] / 2;
    const long long half_items = E * 32;   // work items per stream
    const long long total      = E * 64;   // both streams
    const long long half_off   = E * 512;  // floats

    const int block = 256;
    const int grid  = 8192;                // grid-stride, 8 iters/thread

    edge_embed_kernel<<<grid, block, 0, stream>>>(
        edge_index, radial, ea, na, W, b, out, total, half_items, half_off);
}

// Round 6
// 196.910 us; speedup vs baseline: 1.0194x; 1.0194x over previous
//
#include <hip/hip_runtime.h>

// out[e, k, i, j] = rf[e][i] * na[sender[e]][k] * ea[e][j]
// rf[e][i] = b[i] + sum_m radial[e][m] * W[i][m]
// out offset = e*512 + k*128 + i*16 + j ; duplicated at +E*512.
//
// One thread per (e, i, j4). Stores are non-temporal (global_store_dwordx4 nt):
// the 1 GB output is write-once, never re-read -> bypass L2 allocation.
// R4 post-mortem: splitting the two output streams across blocks regressed
// (-2%); dual-region interleaved nt stores from one thread are optimal here.

typedef float f32x4 __attribute__((ext_vector_type(4)));

__global__ void edge_embed_kernel(const int* __restrict__ edge_index,
                                  const float* __restrict__ radial,
                                  const float* __restrict__ ea,
                                  const float* __restrict__ na,
                                  const float* __restrict__ W,
                                  const float* __restrict__ b,
                                  float* __restrict__ out,
                                  long long total,      // E * 32
                                  long long half_off)   // E * 512
{
    long long u = (long long)blockIdx.x * blockDim.x + threadIdx.x;
    const long long stride = (long long)gridDim.x * blockDim.x;

    for (; u < total; u += stride) {
        const int t = (int)(u & 31);
        const long long e = u >> 5;
        const int i  = t >> 2;
        const int j4 = t & 3;

        // rf[i] = b[i] + radial[e,:] . W[i,:]  (wave-broadcast L1 hits)
        const float* __restrict__ r = radial + e * 8;
        const float* __restrict__ w = W + i * 8;
        float rf = b[i];
        #pragma unroll
        for (int m = 0; m < 8; ++m) rf = fmaf(r[m], w[m], rf);

        const int s = edge_index[e];
        const f32x4 na4 = *reinterpret_cast<const f32x4*>(na + (long long)s * 4);
        const f32x4 ea4 = *reinterpret_cast<const f32x4*>(ea + e * 16 + j4 * 4);

        const long long base = e * 512 + (long long)t * 4;  // floats

        #pragma unroll
        for (int k = 0; k < 4; ++k) {
            const float c = rf * na4[k];
            f32x4 o = c * ea4;
            __builtin_nontemporal_store(o, reinterpret_cast<f32x4*>(out + base + k * 128));
            __builtin_nontemporal_store(o, reinterpret_cast<f32x4*>(out + half_off + base + k * 128));
        }
    }
}

extern "C" void kernel_launch(void* const* d_in, const int* in_sizes, int n_in,
                              void* d_out, int out_size, void* d_ws, size_t ws_size,
                              hipStream_t stream) {
    const int*   edge_index = (const int*)d_in[0];   // (2, E)
    const float* radial     = (const float*)d_in[1]; // (E, 8)
    const float* ea         = (const float*)d_in[2]; // (E, 16)
    const float* na         = (const float*)d_in[3]; // (N, 4)
    const float* W          = (const float*)d_in[4]; // (8, 8)
    const float* b          = (const float*)d_in[5]; // (8,)
    float* out = (float*)d_out;

    const long long E = in_sizes[0] / 2;
    const long long total    = E * 32;    // work items
    const long long half_off = E * 512;   // floats

    const int block = 256;
    const int grid  = 8192;               // grid-stride, 4 iters/thread

    edge_embed_kernel<<<grid, block, 0, stream>>>(
        edge_index, radial, ea, na, W, b, out, total, half_off);
}